// Round 12
// baseline (121.133 us; speedup 1.0000x reference)
//
#include <hip/hip_runtime.h>

// WL-conv factorized:  out[b,c,n,k] = Y0 + e1[c,k]*Y1 + e2[c,k]*Y2 + e3[c,k]*Y3
// with Ym = M^m labels and e_m the elementary symmetric polynomials of
// kernels[c,0..2,k] (per-step operators I + k_t∘M commute).
//
// 7-stage batch-skewed pipeline over stream-ordered kernels (boundary=barrier):
//   S0: pack(b0)                         S4: spmm1(b3)|spmm2(b2)|spmm3c(b1)
//   S1: spmm1(b0)|pack(b1)               S5: spmm2(b3)|spmm3c(b2)
//   S2: spmm1(b1)|spmm2(b0)|pack(b2)     S6: spmm3c(b3)
//   S3: spmm1(b2)|spmm2(b1)|spmm3c(b0)|pack(b3)
// pack is HBM-bound (~10.5us/batch), spmm is VALU/latency-bound (~4us/job):
// co-scheduling them in one kernel overlaps the idle pipes. spmm jobs get low
// blockIdx (launch first); pack grid-strides on 1024 blocks.
// Device code (int4 pack, ypos-permuted swizzled Y, depth-4 pipelined MFMA
// spmm, fused combine) is identical to R11's verified kernels.
//
// d_out (8 MB): final output only.
// d_ws: bits 8MB | ysw0 | ysw1 | ysw2 (0.5 MB each, swizzled bf16).

#define BB 4
#define NN 4096
#define KK 16
#define CC 8
#define TT 3
#define WPR (NN / 64)
#define YSWZ (KK * NN)   // u16 elements per batch in swizzled Y (65536)
#define PACKB 1024       // pack blocks per stage

typedef unsigned long long u64;
typedef unsigned int u32;
typedef unsigned short u16;
typedef __attribute__((ext_vector_type(8))) short s16x8;
typedef __attribute__((ext_vector_type(4))) float f32x4v;

__device__ __forceinline__ u32 bf16_rne(float f) {
    u32 u = __float_as_uint(f);
    return (u + 0x7FFFu + ((u >> 16) & 1u)) >> 16;
}
__device__ __forceinline__ float bf16_f32(u32 h) {
    return __uint_as_float(h << 16);
}
__device__ __forceinline__ long ypos(int f, int s) {
    return ((long)(s >> 8) << 12) + (s & 3) * 1024 + ((s >> 7) & 1) * 512 +
           f * 32 + ((s >> 5) & 3) * 8 + ((s >> 2) & 7);
}

// byte (8 mask bits) -> 8 bf16 {0,1} packed in s16x8 (elem i = bit i)
__device__ __forceinline__ s16x8 expand8(u32 byt) {
    u32 n0 = byt & 0xFu, n1 = (byt >> 4) & 0xFu;
    u32 t0 = (n0 * 0x204081u) & 0x01010101u;
    u32 t1 = (n1 * 0x204081u) & 0x01010101u;
    u32 m0 = (t0 << 7) - t0;
    u32 m1 = (t1 << 7) - t1;
    union { u32 w[4]; s16x8 v; } u;
    u.w[0] = __builtin_amdgcn_perm(0u, m0, 0x0C010C00u) << 7;
    u.w[1] = __builtin_amdgcn_perm(0u, m0, 0x0C030C02u) << 7;
    u.w[2] = __builtin_amdgcn_perm(0u, m1, 0x0C010C00u) << 7;
    u.w[3] = __builtin_amdgcn_perm(0u, m1, 0x0C030C02u) << 7;
    return u.v;
}

// ------------------------------------------------- pack one batch (device) --
__device__ __forceinline__ void pack_job(
    const int* __restrict__ lig, u64* __restrict__ bits,
    const float* __restrict__ labels, u16* __restrict__ ysw0,
    int b, int lb, int tid)
{
    // prep: labels -> swizzled bf16 Y0 for this batch (first 64 pack blocks)
    if (lb < 64) {
        int t  = lb * 256 + tid;                         // 0..16383
        int s4 = (t & (NN / 4 - 1)) * 4;
        int f  = t >> 10;
        long base = (long)b * YSWZ + ypos(f, s4);
        const float* lp = labels + ((long)b * NN + s4) * KK + f;
#pragma unroll
        for (int j = 0; j < 4; ++j)
            ysw0[base + j * 1024] = (u16)bf16_rne(lp[j * KK]);
    }
    const int total = (WPR / 4) * NN;                    // 65536 int4-groups
    int  wid  = (lb * 256 + tid) >> 6;
    int  lane = tid & 63;
    const int nw = (PACKB * 256) >> 6;                   // 4096 wave-slots
    for (int o = wid; o < total; o += nw) {
        int n  = o & (NN - 1);
        int w4 = o >> 12;
        int4 v = *(const int4*)(lig + ((long)b * NN + n) * NN + w4 * 256 + lane * 4);
        u64 m0 = __ballot(v.x >= 1);
        u64 m1 = __ballot(v.y >= 1);
        u64 m2 = __ballot(v.z >= 1);
        u64 m3 = __ballot(v.w >= 1);
        if (lane == 0) {
            u64* bw = bits + ((long)b * WPR + 4 * w4) * NN + n;
            bw[0] = m0; bw[NN] = m1; bw[2 * NN] = m2; bw[3 * NN] = m3;
        }
    }
}

// ------------------------------------------------- spmm one batch (device) --
// PASS 1/2: yin->yout swizzled bf16.  PASS 3: fused combine epilogue.
template<int PASS>
__device__ __forceinline__ void spmm_job(
    const u64* __restrict__ bits, const u16* __restrict__ yin,
    u16* __restrict__ yout, const u16* __restrict__ ysw1,
    const u16* __restrict__ ysw2, const float* __restrict__ labels,
    const float* __restrict__ ker, float* __restrict__ out,
    int b, int rt, int tid, float (*red)[4][64])
{
    const int lane = tid & 63, ss = tid >> 6;
    const int n16 = lane & 15, g = lane >> 4;
    const int row0 = rt * 16;

    const u64* bb = bits + ((long)b * WPR + ss * 16) * NN + row0 + n16;
    u64 wcs[16];
#pragma unroll
    for (int wi = 0; wi < 16; ++wi) wcs[wi] = bb[(long)wi * NN];

    const u16* yb = yin + (long)b * YSWZ + (ss * 16) * 1024 + n16 * 32 + g * 8;
    s16x8 p0[4], p1[4];
#pragma unroll
    for (int i = 0; i < 4; ++i) {
        p0[i] = *(const s16x8*)(yb + i * 1024);
        p1[i] = *(const s16x8*)(yb + i * 1024 + 512);
    }

    f32x4v accA = {0.f, 0.f, 0.f, 0.f}, accB = {0.f, 0.f, 0.f, 0.f};
#pragma unroll
    for (int wi = 0; wi < 16; ++wi) {
        const int slot = wi & 3;
        s16x8 b0 = p0[slot], b1 = p1[slot];
        if (wi + 4 < 16) {
            p0[slot] = *(const s16x8*)(yb + (wi + 4) * 1024);
            p1[slot] = *(const s16x8*)(yb + (wi + 4) * 1024 + 512);
        }
        u64 h = wcs[wi] >> (g * 8);
        u32 lo8 = (u32)h & 0xFFu;
        u32 hi8 = ((u32)(h >> 32)) & 0xFFu;
        accA = __builtin_amdgcn_mfma_f32_16x16x32_bf16(expand8(lo8), b0, accA, 0, 0, 0);
        accB = __builtin_amdgcn_mfma_f32_16x16x32_bf16(expand8(hi8), b1, accB, 0, 0, 0);
    }

    f32x4v acc;
#pragma unroll
    for (int r = 0; r < 4; ++r) acc[r] = accA[r] + accB[r];

    if (ss != 0) {
#pragma unroll
        for (int r = 0; r < 4; ++r) red[ss - 1][r][lane] = acc[r];
    }
    __syncthreads();
    if (ss == 0) {
#pragma unroll
        for (int r = 0; r < 4; ++r)
            acc[r] += red[0][r][lane] + red[1][r][lane] + red[2][r][lane];

        const int s0 = row0 + 4 * g;                     // mult of 4: +r*1024
        const long base = (long)b * YSWZ + ypos(n16, s0);
        if (PASS < 3) {
#pragma unroll
            for (int r = 0; r < 4; ++r)
                yout[base + r * 1024] = (u16)bf16_rne(acc[r]);
        } else {
            float e1v[CC], e2v[CC], e3v[CC];
#pragma unroll
            for (int c = 0; c < CC; ++c) {
                float a = ker[(c * TT + 0) * KK + n16];
                float d = ker[(c * TT + 1) * KK + n16];
                float e = ker[(c * TT + 2) * KK + n16];
                e1v[c] = a + d + e;
                e2v[c] = a * d + a * e + d * e;
                e3v[c] = a * d * e;
            }
            float y1v[4], y2v[4];
#pragma unroll
            for (int r = 0; r < 4; ++r) {
                y1v[r] = bf16_f32(ysw1[base + r * 1024]);
                y2v[r] = bf16_f32(ysw2[base + r * 1024]);
            }
#pragma unroll
            for (int r = 0; r < 4; ++r) {
                int row = s0 + r;
                float y0 = labels[((long)b * NN + row) * KK + n16];
#pragma unroll
                for (int c = 0; c < CC; ++c)
                    out[(((long)b * CC + c) * NN + row) * KK + n16] =
                        y0 + e1v[c] * y1v[r] + e2v[c] * y2v[r] + e3v[c] * acc[r];
            }
        }
    }
}

// ------------------------------------------------------------ stage kernel --
// Routing: spmm jobs occupy low blockIdx (256 blocks each, launch first);
// pack occupies the last PACKB blocks. NS = number of spmm jobs this stage;
// PB = batch to pack (-1 none). Job j (0..NS-1) = pass (FIRSTPASS+j... ) —
// encode explicitly: jobs are (pass, batch) pairs.
template<int STAGE>
__global__ __launch_bounds__(256, 4)
void stage_k(const int* __restrict__ lig, const float* __restrict__ labels,
             const float* __restrict__ ker, float* __restrict__ out,
             u64* __restrict__ bits, u16* __restrict__ ysw0,
             u16* __restrict__ ysw1, u16* __restrict__ ysw2)
{
    __shared__ float red[3][4][64];
    const int bid = blockIdx.x;
    const int tid = threadIdx.x;
    const int job = bid >> 8;        // 256 blocks per spmm job
    const int rt  = bid & 255;

    // stage tables: {#spmm jobs, pack batch, first spmm "chain position"}
    // chain position p for job j means: pass = j+1 ... encoded per stage:
    //   stage S has spmm jobs: pass = j+1, batch = (S-1) - j   (valid ones)
    constexpr int NS   = (STAGE == 0) ? 0 : (STAGE <= 3) ? STAGE : 7 - STAGE;
    constexpr int PB   = (STAGE <= 3) ? STAGE : -1;
    // first job's pass: stages 1..3 start at pass 1; stage 4: pass 1; 5: 2; 6: 3
    constexpr int P0   = (STAGE <= 4) ? 1 : STAGE - 3;
    // first job's batch: stage s job j: batch = (s - P0 + 1) - 1 - j? derive:
    // S1: (p1,b0); S2: (p1,b1),(p2,b0); S3: (p1,b2),(p2,b1),(p3,b0)
    // S4: (p1,b3),(p2,b2),(p3,b1); S5: (p2,b3),(p3,b2); S6: (p3,b3)
    // pass = P0 + j ; batch = STAGE - pass  (check: S4 j0: p1,b3 ✓ S6: p3,b3 ✓)

    if (job < NS) {
        const int pass = P0 + job;
        const int b    = STAGE - pass;
        if (pass == 1)
            spmm_job<1>(bits, ysw0, ysw1, nullptr, nullptr, nullptr, nullptr,
                        nullptr, b, rt, tid, red);
        else if (pass == 2)
            spmm_job<2>(bits, ysw1, ysw2, nullptr, nullptr, nullptr, nullptr,
                        nullptr, b, rt, tid, red);
        else
            spmm_job<3>(bits, ysw2, nullptr, ysw1, ysw2, labels, ker, out,
                        b, rt, tid, red);
    } else if (PB >= 0) {
        pack_job(lig, bits, labels, ysw0, PB, bid - NS * 256, tid);
    }
}

// --------------------------------------------------------------- launch -----
extern "C" void kernel_launch(void* const* d_in, const int* in_sizes, int n_in,
                              void* d_out, int out_size, void* d_ws, size_t ws_size,
                              hipStream_t stream) {
    const float* labels = (const float*)d_in[0];   // [B,N,K] f32
    const int*   lig    = (const int*)d_in[1];     // [B,N,N] i32
    const float* ker    = (const float*)d_in[2];   // [C,T,K] f32
    float* out = (float*)d_out;

    u64* bits = (u64*)d_ws;                        // 8 MB
    u16* ysw0 = (u16*)((char*)d_ws + (long)BB * WPR * NN * 8);
    u16* ysw1 = ysw0 + (long)BB * YSWZ;
    u16* ysw2 = ysw1 + (long)BB * YSWZ;

#define LAUNCH_STAGE(S, NSPMM, HASPACK)                                     \
    hipLaunchKernelGGL((stage_k<S>),                                        \
                       dim3((NSPMM) * 256 + ((HASPACK) ? PACKB : 0)),       \
                       dim3(256), 0, stream,                                \
                       lig, labels, ker, out, bits, ysw0, ysw1, ysw2)

    LAUNCH_STAGE(0, 0, 1);   // pack b0
    LAUNCH_STAGE(1, 1, 1);   // spmm1(b0) | pack b1
    LAUNCH_STAGE(2, 2, 1);   // spmm1(b1) spmm2(b0) | pack b2
    LAUNCH_STAGE(3, 3, 1);   // spmm1(b2) spmm2(b1) spmm3c(b0) | pack b3
    LAUNCH_STAGE(4, 3, 0);   // spmm1(b3) spmm2(b2) spmm3c(b1)
    LAUNCH_STAGE(5, 2, 0);   // spmm2(b3) spmm3c(b2)
    LAUNCH_STAGE(6, 1, 0);   // spmm3c(b3)
#undef LAUNCH_STAGE
}